// Round 6
// baseline (278.084 us; speedup 1.0000x reference)
//
#include <hip/hip_runtime.h>
#include <hip/hip_bf16.h>
#include <math.h>

// ---------------------------------------------------------------------------
// GIN 2-layer forward. CSR via two-level counting sort (packed 26-bit pairs),
// bf16 gathers (f32 sums), bf16 MFMA GEMMs, aggregate-after-projection for
// conv2:  (h + A h) @ W1b == m + A m  with  m = h @ W1b   (linearity).
// N=100000, E=1200000, IN=64, HID=128, OUT=40.
// ---------------------------------------------------------------------------

#define WS_ALIGN 256
#define NBLK_C 256          // edge-chunk blocks for bucket sort
#define NPB_SHIFT 9         // 512 nodes per coarse bucket
#define NPB 512
#define SCAN_T 256
#define SCAN_E 1024         // elements per scan block

typedef __attribute__((ext_vector_type(8))) __bf16 bf16x8;
typedef __attribute__((ext_vector_type(4))) float f32x4;

__device__ inline unsigned short f2b(float f) {      // RNE f32->bf16
  unsigned int x = __float_as_uint(f);
  return (unsigned short)((x + 0x7fffu + ((x >> 16) & 1u)) >> 16);
}
__device__ inline float b2f(unsigned short u) {
  return __uint_as_float(((unsigned int)u) << 16);
}

// --- dtype sniff: edge_index may be int64 (ref) or int32 (x64-disabled JAX).
__global__ __launch_bounds__(256) void sniff_kernel(const unsigned int* __restrict__ ew,
                                                    unsigned int* __restrict__ flag, int E) {
  unsigned int acc = 0;
  int i = threadIdx.x;
  for (int j = 0; j < 16; ++j) {
    long long s = ((long long)(i * 16 + j) * 292 + 7) % E;
    acc |= ew[2 * (size_t)s + 1];
  }
  if (acc) atomicOr(flag, 1u);   // nonzero -> int32 layout
}

// --- K1: per-chunk coarse histogram.
__global__ __launch_bounds__(256) void bhist_kernel(
    const unsigned int* __restrict__ ew, const unsigned int* __restrict__ flag,
    int* __restrict__ gcount, int E, int NB) {
  extern __shared__ int hist[];
  const bool is64 = (*flag == 0u);
  const int t = threadIdx.x, blk = blockIdx.x;
  for (int i = t; i < NB; i += 256) hist[i] = 0;
  __syncthreads();
  const int chunk = (E + NBLK_C - 1) / NBLK_C;
  const int beg = blk * chunk, end = min(E, beg + chunk);
  for (int e = beg + t; e < end; e += 256) {
    int d = is64 ? (int)ew[2 * (size_t)(E + e)] : (int)ew[(size_t)E + e];
    atomicAdd(&hist[d >> NPB_SHIFT], 1);
  }
  __syncthreads();
  for (int i = t; i < NB; i += 256) gcount[i * NBLK_C + blk] = hist[i];
}

// --- K2: 3-pass parallel exclusive scan of gcount[tot] in place.
__global__ __launch_bounds__(SCAN_T) void pscan1_kernel(const int* __restrict__ g,
                                                        int* __restrict__ bsum, int tot) {
  __shared__ int s[SCAN_T];
  int b = blockIdx.x, t = threadIdx.x;
  int base = b * SCAN_E + t * 4;
  int v = 0;
#pragma unroll
  for (int k = 0; k < 4; ++k) { int i = base + k; if (i < tot) v += g[i]; }
  s[t] = v; __syncthreads();
  for (int off = SCAN_T / 2; off >= 1; off >>= 1) {
    if (t < off) s[t] += s[t + off];
    __syncthreads();
  }
  if (t == 0) bsum[b] = s[0];
}

__global__ void pscan2_kernel(int* __restrict__ bsum, int nb) {
  if (blockIdx.x == 0 && threadIdx.x == 0) {
    int run = 0;
    for (int i = 0; i < nb; ++i) { int v = bsum[i]; bsum[i] = run; run += v; }
    bsum[nb] = run;
  }
}

__global__ __launch_bounds__(SCAN_T) void pscan3_kernel(
    int* __restrict__ g, const int* __restrict__ bsum, int tot) {
  __shared__ int s[SCAN_T];
  int b = blockIdx.x, t = threadIdx.x;
  int base = b * SCAN_E + t * 4;
  int d[4]; int v = 0;
#pragma unroll
  for (int k = 0; k < 4; ++k) { int i = base + k; d[k] = (i < tot) ? g[i] : 0; v += d[k]; }
  s[t] = v; __syncthreads();
  for (int off = 1; off < SCAN_T; off <<= 1) {
    int u = (t >= off) ? s[t - off] : 0;
    __syncthreads();
    s[t] += u;
    __syncthreads();
  }
  int exc = s[t] - v + bsum[b];
#pragma unroll
  for (int k = 0; k < 4; ++k) {
    int i = base + k;
    if (i < tot) { g[i] = exc; exc += d[k]; }
  }
}

// --- K3: scatter packed (src<<9 | dst&511) bucket-major using LDS cursors.
__global__ __launch_bounds__(256) void bscatter_kernel(
    const unsigned int* __restrict__ ew, const unsigned int* __restrict__ flag,
    const int* __restrict__ gscan, unsigned int* __restrict__ pairs, int E, int NB) {
  extern __shared__ int cur[];
  const bool is64 = (*flag == 0u);
  const int t = threadIdx.x, blk = blockIdx.x;
  for (int i = t; i < NB; i += 256) cur[i] = gscan[i * NBLK_C + blk];
  __syncthreads();
  const int chunk = (E + NBLK_C - 1) / NBLK_C;
  const int beg = blk * chunk, end = min(E, beg + chunk);
  for (int e = beg + t; e < end; e += 256) {
    unsigned int s, d;
    if (is64) { s = ew[2 * (size_t)e]; d = ew[2 * (size_t)(E + e)]; }
    else      { s = ew[(size_t)e];     d = ew[(size_t)E + e]; }
    int pos = atomicAdd(&cur[d >> NPB_SHIFT], 1);
    pairs[pos] = (s << NPB_SHIFT) | (d & (NPB - 1));
  }
}

// --- K4: per-bucket LDS counting sort -> rowptr (direct) + dense col writes.
__global__ __launch_bounds__(256) void bsort_kernel(
    const unsigned int* __restrict__ pairs, const int* __restrict__ gscan,
    int* __restrict__ rowptr, int* __restrict__ col, int E, int N, int NB) {
  __shared__ int cnt[NPB];
  __shared__ int scn[NPB];
  __shared__ int cur[NPB];
  __shared__ int part[256];
  const int t = threadIdx.x, b = blockIdx.x;
  const int base = gscan[(size_t)b * NBLK_C];
  const int bend = (b + 1 < NB) ? gscan[(size_t)(b + 1) * NBLK_C] : E;
  const int n0 = b << NPB_SHIFT;

  cnt[2 * t] = 0; cnt[2 * t + 1] = 0;
  __syncthreads();
  for (int j = base + t; j < bend; j += 256)
    atomicAdd(&cnt[pairs[j] & (NPB - 1)], 1);
  __syncthreads();

  int c0 = cnt[2 * t], c1 = cnt[2 * t + 1];
  part[t] = c0 + c1;
  __syncthreads();
  for (int off = 1; off < 256; off <<= 1) {
    int u = (t >= off) ? part[t - off] : 0;
    __syncthreads();
    part[t] += u;
    __syncthreads();
  }
  int exc = part[t] - (c0 + c1);
  scn[2 * t] = exc; scn[2 * t + 1] = exc + c0;
  cur[2 * t] = base + exc; cur[2 * t + 1] = base + exc + c0;

  int g0 = n0 + 2 * t, g1 = n0 + 2 * t + 1;
  if (g0 < N) rowptr[g0] = base + scn[2 * t];
  if (g1 < N) rowptr[g1] = base + scn[2 * t + 1];
  if (b == NB - 1 && t == 0) rowptr[N] = E;
  __syncthreads();

  for (int j = base + t; j < bend; j += 256) {
    unsigned int p = pairs[j];
    int pos = atomicAdd(&cur[p & (NPB - 1)], 1);
    col[pos] = (int)(p >> NPB_SHIFT);
  }
}

// --- cast x (f32) -> xb (bf16), vectorized
__global__ __launch_bounds__(256) void castx_kernel(
    const float4* __restrict__ X, ushort4* __restrict__ XB, int tot4) {
  int i = blockIdx.x * 256 + threadIdx.x;
  if (i >= tot4) return;
  float4 v = X[i];
  ushort4 r;
  r.x = f2b(v.x); r.y = f2b(v.y); r.z = f2b(v.z); r.w = f2b(v.w);
  XB[i] = r;
}

// --- weight transpose + cast: Wt[fo][k] = bf16(W[k][fo]), zero-pad fo>=Fo
__global__ __launch_bounds__(256) void transw_kernel(
    const float* __restrict__ W, unsigned short* __restrict__ Wt,
    int Fi, int Fo, int FoPad) {
  int i = blockIdx.x * 256 + threadIdx.x;
  if (i >= FoPad * Fi) return;
  int fo = i / Fi, k = i - fo * Fi;
  float v = (fo < Fo) ? W[(size_t)k * Fo + fo] : 0.f;
  Wt[i] = f2b(v);
}

// --- gather over bf16 [N,64] rows (128 B lines): out[n] = X[n] + sum X[col[j]]
// One wave per node, lane = feature. OUT_F32 selects output dtype.
template<bool OUT_F32>
__global__ __launch_bounds__(256) void gatherB_kernel(
    const unsigned short* __restrict__ X, const int* __restrict__ rowptr,
    const int* __restrict__ col, void* __restrict__ outv, int N) {
  const int lane = threadIdx.x & 63;
  const int n = blockIdx.x * 4 + (threadIdx.x >> 6);
  if (n >= N) return;
  const int beg = rowptr[n], end = rowptr[n + 1];
  float a0 = b2f(X[(size_t)n * 64 + lane]), a1 = 0.f, a2 = 0.f, a3 = 0.f;
  int j = beg;
  for (; j + 4 <= end; j += 4) {
    int c0 = col[j], c1 = col[j + 1], c2 = col[j + 2], c3 = col[j + 3];
    a0 += b2f(X[(size_t)c0 * 64 + lane]);
    a1 += b2f(X[(size_t)c1 * 64 + lane]);
    a2 += b2f(X[(size_t)c2 * 64 + lane]);
    a3 += b2f(X[(size_t)c3 * 64 + lane]);
  }
  for (; j < end; ++j) a0 += b2f(X[(size_t)col[j] * 64 + lane]);
  float r = a0 + a1 + a2 + a3;
  if (OUT_F32) ((float*)outv)[(size_t)n * 64 + lane] = r;
  else         ((unsigned short*)outv)[(size_t)n * 64 + lane] = f2b(r);
}

// --- bf16 MFMA GEMM: out[n][fo] = act(A[n]@W + b). Block: 4 waves x 16 nodes.
// Wt (B^T, bf16 [FoPad][Fi]) staged in LDS with XOR swizzle; A-frags from global.
template<int Fi, int FoPad, bool RELU>
__global__ __launch_bounds__(256) void gemm_mfma(
    const unsigned short* __restrict__ A, const unsigned short* __restrict__ WtG,
    const float* __restrict__ bias, unsigned short* __restrict__ out,
    int N, int Fo) {
  __shared__ unsigned short Wlds[FoPad * Fi];
  const int t = threadIdx.x;
  const int n0 = blockIdx.x * 64;

  constexpr int NCH = FoPad * Fi / 8;       // 16B chunks
  constexpr int CPR = Fi / 8;               // chunks per row
  for (int c = t; c < NCH; c += 256) {
    int row = c / CPR;
    uint4 v = ((const uint4*)WtG)[c];
    int boff = (c * 16) ^ ((row & 7) << 4);
    *(uint4*)((char*)Wlds + boff) = v;
  }
  __syncthreads();

  const int l = t & 63, w = t >> 6;
  const int kgrp = l >> 4;                  // 0..3
  const int rc = l & 15;
  int arow = n0 + w * 16 + rc;
  int arowc = arow < N ? arow : N - 1;

  constexpr int NF = FoPad / 16;
  f32x4 acc[NF];
#pragma unroll
  for (int nf = 0; nf < NF; ++nf) acc[nf] = (f32x4){0.f, 0.f, 0.f, 0.f};

#pragma unroll
  for (int k0 = 0; k0 < Fi; k0 += 32) {
    bf16x8 a = *(const bf16x8*)(A + (size_t)arowc * Fi + k0 + kgrp * 8);
#pragma unroll
    for (int nf = 0; nf < NF; ++nf) {
      int frow = nf * 16 + rc;
      int boff = ((frow * Fi + k0 + kgrp * 8) * 2) ^ ((frow & 7) << 4);
      bf16x8 b = *(const bf16x8*)((const char*)Wlds + boff);
      acc[nf] = __builtin_amdgcn_mfma_f32_16x16x32_bf16(a, b, acc[nf], 0, 0, 0);
    }
  }

#pragma unroll
  for (int nf = 0; nf < NF; ++nf) {
    int fo = nf * 16 + rc;
    float bs = (fo < Fo) ? bias[fo] : 0.f;
#pragma unroll
    for (int q = 0; q < 4; ++q) {
      int n = n0 + w * 16 + kgrp * 4 + q;
      if (n < N && fo < Fo) {
        float v = acc[nf][q] + bs;
        if (RELU) v = fmaxf(v, 0.f);
        out[(size_t)n * Fo + fo] = f2b(v);
      }
    }
  }
}

// --- final: per node, v = relu(ham[0:40] + b1b); z = v@W2b + b2b; log_softmax.
// ham is f32 [N,64] (cols 40.. are zero/ignored). One wave per node.
__global__ __launch_bounds__(256) void gemm_lsm_kernel(
    const float* __restrict__ HAM, const float* __restrict__ b1,
    const float* __restrict__ W, const float* __restrict__ bias,
    float* __restrict__ out, int N) {
  __shared__ float Wl[40 * 40];
  __shared__ float bl[40];
  __shared__ float b1l[40];
  int t = threadIdx.x;
  for (int i = t; i < 1600; i += 256) Wl[i] = W[i];
  if (t < 40) { bl[t] = bias[t]; b1l[t] = b1[t]; }
  __syncthreads();

  const int lane = t & 63;
  const int wid  = blockIdx.x * 4 + (t >> 6);
  const int nw   = gridDim.x * 4;
  for (int n = wid; n < N; n += nw) {
    const float* a = HAM + (size_t)n * 64;
    float acc = (lane < 40) ? bl[lane] : 0.f;
    if (lane < 40) {
#pragma unroll 8
      for (int k = 0; k < 40; ++k) {
        float v = fmaxf(a[k] + b1l[k], 0.f);
        acc += v * Wl[k * 40 + lane];
      }
    }
    float m = (lane < 40) ? acc : -3.4e38f;
#pragma unroll
    for (int o = 32; o >= 1; o >>= 1) m = fmaxf(m, __shfl_xor(m, o, 64));
    float ex = (lane < 40) ? expf(acc - m) : 0.f;
    float ssum = ex;
#pragma unroll
    for (int o = 32; o >= 1; o >>= 1) ssum += __shfl_xor(ssum, o, 64);
    if (lane < 40) out[(size_t)n * 40 + lane] = acc - m - logf(ssum);
  }
}

extern "C" void kernel_launch(void* const* d_in, const int* in_sizes, int n_in,
                              void* d_out, int out_size, void* d_ws, size_t ws_size,
                              hipStream_t stream) {
  const float*        x   = (const float*)d_in[0];
  const unsigned int* ew  = (const unsigned int*)d_in[1];
  const float*        W1a = (const float*)d_in[2];
  const float*        b1a = (const float*)d_in[3];
  const float*        W2a = (const float*)d_in[4];
  const float*        b2a = (const float*)d_in[5];
  const float*        W1b = (const float*)d_in[6];
  const float*        b1b = (const float*)d_in[7];
  const float*        W2b = (const float*)d_in[8];
  const float*        b2b = (const float*)d_in[9];

  const int N = in_sizes[0] / 64;     // 100000
  const int E = in_sizes[1] / 2;      // 1200000
  const int NB = (N + NPB - 1) >> NPB_SHIFT;   // coarse buckets (196)
  float* out = (float*)d_out;

  char* ws = (char*)d_ws;
  size_t off = 0;
  auto alloc = [&](size_t bytes) {
    char* p = ws + off;
    off += (bytes + WS_ALIGN - 1) & ~(size_t)(WS_ALIGN - 1);
    return p;
  };
  unsigned int*  flag   = (unsigned int*)alloc(4);      // offset 0
  float*         zbias  = (float*)alloc(256);           // offset 256, zeroed
  int*           rowptr = (int*)alloc((size_t)(N + 2) * 4);
  int*           gscan  = (int*)alloc((size_t)NB * NBLK_C * 4);
  int*           bsum2  = (int*)alloc(256 * 4);
  int*           col    = (int*)alloc((size_t)E * 4);
  unsigned short* Wt1   = (unsigned short*)alloc((size_t)128 * 64 * 2);
  unsigned short* Wt2   = (unsigned short*)alloc((size_t)128 * 128 * 2);
  unsigned short* Wt3   = (unsigned short*)alloc((size_t)64 * 128 * 2);
  unsigned short* xb    = (unsigned short*)alloc((size_t)N * 64 * 2);  // bf16 x
  unsigned short* xa    = (unsigned short*)alloc((size_t)N * 64 * 2);  // x+agg1
  unsigned short* mid   = (unsigned short*)alloc((size_t)N * 128 * 2);
  unsigned short* h     = (unsigned short*)alloc((size_t)N * 128 * 2);
  // aliases (lifetimes disjoint):
  unsigned int* pairs = (unsigned int*)mid;        // CSR build staging (4.8 MB)
  unsigned short* m   = mid;                       // m = h@W1b padded [N,64] bf16
  float* ham          = (float*)xb;                // m + A m, f32 [N,64] (25.6 MB over xb+xa)

  hipMemsetAsync(ws, 0, 512, stream);              // flag + zbias
  sniff_kernel<<<1, 256, 0, stream>>>(ew, flag, E);

  // --- CSR build: two-level counting sort (packed pairs)
  const size_t ldsNB = (size_t)NB * 4;
  const int tot = NB * NBLK_C;
  const int nb2 = (tot + SCAN_E - 1) / SCAN_E;
  bhist_kernel<<<NBLK_C, 256, ldsNB, stream>>>(ew, flag, gscan, E, NB);
  pscan1_kernel<<<nb2, SCAN_T, 0, stream>>>(gscan, bsum2, tot);
  pscan2_kernel<<<1, 64, 0, stream>>>(bsum2, nb2);
  pscan3_kernel<<<nb2, SCAN_T, 0, stream>>>(gscan, bsum2, tot);
  bscatter_kernel<<<NBLK_C, 256, ldsNB, stream>>>(ew, flag, gscan, pairs, E, NB);
  bsort_kernel<<<NB, 256, 0, stream>>>(pairs, gscan, rowptr, col, E, N, NB);

  // casts / weight transposes (bf16)
  castx_kernel<<<(N * 16 + 255) / 256, 256, 0, stream>>>((const float4*)x, (ushort4*)xb, N * 16);
  transw_kernel<<<(128 * 64 + 255) / 256, 256, 0, stream>>>(W1a, Wt1, 64, 128, 128);
  transw_kernel<<<(128 * 128 + 255) / 256, 256, 0, stream>>>(W2a, Wt2, 128, 128, 128);
  transw_kernel<<<(64 * 128 + 255) / 256, 256, 0, stream>>>(W1b, Wt3, 128, 40, 64);

  const int gGather = (N + 3) / 4;
  const int gGemm = (N + 63) / 64;

  // conv1: xa = x + A x ; mid = relu(xa@W1a+b1a) ; h = relu(mid@W2a+b2a)
  gatherB_kernel<false><<<gGather, 256, 0, stream>>>(xb, rowptr, col, xa, N);
  gemm_mfma<64, 128, true><<<gGemm, 256, 0, stream>>>(xa, Wt1, b1a, mid, N, 128);
  gemm_mfma<128, 128, true><<<gGemm, 256, 0, stream>>>(mid, Wt2, b2a, h, N, 128);

  // conv2 (aggregate-after-projection): m = h@W1b (padded 64 cols, no bias)
  gemm_mfma<128, 64, false><<<gGemm, 256, 0, stream>>>(h, Wt3, zbias, m, N, 64);
  // ham = m + A m  (f32)
  gatherB_kernel<true><<<gGather, 256, 0, stream>>>(m, rowptr, col, ham, N);
  // out = log_softmax(relu(ham+b1b)@W2b + b2b)
  gemm_lsm_kernel<<<1024, 256, 0, stream>>>(ham, b1b, W2b, b2b, out, N);
}

// Round 7
// 235.127 us; speedup vs baseline: 1.1827x; 1.1827x over previous
//
#include <hip/hip_runtime.h>
#include <hip/hip_bf16.h>
#include <math.h>

// ---------------------------------------------------------------------------
// GIN 2-layer forward. CSR via two-level counting sort (packed 26-bit pairs),
// bf16 gathers (f32 sums), bf16 MFMA GEMMs, aggregate-after-projection for
// conv2 ((h + A h)@W1b == m + A m, m = h@W1b), fused MFMA final GEMM+softmax.
// N=100000, E=1200000, IN=64, HID=128, OUT=40.
// ---------------------------------------------------------------------------

#define WS_ALIGN 256
#define NBLK_C 256          // edge-chunk blocks for bucket sort
#define NPB_SHIFT 9         // 512 nodes per coarse bucket
#define NPB 512
#define SCAN_T 256
#define SCAN_E 1024         // elements per scan block

typedef __attribute__((ext_vector_type(8))) __bf16 bf16x8;
typedef __attribute__((ext_vector_type(4))) float f32x4;

__device__ inline unsigned short f2b(float f) {      // RNE f32->bf16
  unsigned int x = __float_as_uint(f);
  return (unsigned short)((x + 0x7fffu + ((x >> 16) & 1u)) >> 16);
}
__device__ inline float b2f(unsigned short u) {
  return __uint_as_float(((unsigned int)u) << 16);
}

// --- dtype sniff: edge_index may be int64 (ref) or int32 (x64-disabled JAX).
__global__ __launch_bounds__(256) void sniff_kernel(const unsigned int* __restrict__ ew,
                                                    unsigned int* __restrict__ flag, int E) {
  unsigned int acc = 0;
  int i = threadIdx.x;
  for (int j = 0; j < 16; ++j) {
    long long s = ((long long)(i * 16 + j) * 292 + 7) % E;
    acc |= ew[2 * (size_t)s + 1];
  }
  if (acc) atomicOr(flag, 1u);   // nonzero -> int32 layout
}

// --- K1: per-chunk coarse histogram.
__global__ __launch_bounds__(256) void bhist_kernel(
    const unsigned int* __restrict__ ew, const unsigned int* __restrict__ flag,
    int* __restrict__ gcount, int E, int NB) {
  extern __shared__ int hist[];
  const bool is64 = (*flag == 0u);
  const int t = threadIdx.x, blk = blockIdx.x;
  for (int i = t; i < NB; i += 256) hist[i] = 0;
  __syncthreads();
  const int chunk = (E + NBLK_C - 1) / NBLK_C;
  const int beg = blk * chunk, end = min(E, beg + chunk);
  for (int e = beg + t; e < end; e += 256) {
    int d = is64 ? (int)ew[2 * (size_t)(E + e)] : (int)ew[(size_t)E + e];
    atomicAdd(&hist[d >> NPB_SHIFT], 1);
  }
  __syncthreads();
  for (int i = t; i < NB; i += 256) gcount[i * NBLK_C + blk] = hist[i];
}

// --- K2: 3-pass parallel exclusive scan of gcount[tot] in place.
__global__ __launch_bounds__(SCAN_T) void pscan1_kernel(const int* __restrict__ g,
                                                        int* __restrict__ bsum, int tot) {
  __shared__ int s[SCAN_T];
  int b = blockIdx.x, t = threadIdx.x;
  int base = b * SCAN_E + t * 4;
  int v = 0;
#pragma unroll
  for (int k = 0; k < 4; ++k) { int i = base + k; if (i < tot) v += g[i]; }
  s[t] = v; __syncthreads();
  for (int off = SCAN_T / 2; off >= 1; off >>= 1) {
    if (t < off) s[t] += s[t + off];
    __syncthreads();
  }
  if (t == 0) bsum[b] = s[0];
}

__global__ void pscan2_kernel(int* __restrict__ bsum, int nb) {
  if (blockIdx.x == 0 && threadIdx.x == 0) {
    int run = 0;
    for (int i = 0; i < nb; ++i) { int v = bsum[i]; bsum[i] = run; run += v; }
    bsum[nb] = run;
  }
}

__global__ __launch_bounds__(SCAN_T) void pscan3_kernel(
    int* __restrict__ g, const int* __restrict__ bsum, int tot) {
  __shared__ int s[SCAN_T];
  int b = blockIdx.x, t = threadIdx.x;
  int base = b * SCAN_E + t * 4;
  int d[4]; int v = 0;
#pragma unroll
  for (int k = 0; k < 4; ++k) { int i = base + k; d[k] = (i < tot) ? g[i] : 0; v += d[k]; }
  s[t] = v; __syncthreads();
  for (int off = 1; off < SCAN_T; off <<= 1) {
    int u = (t >= off) ? s[t - off] : 0;
    __syncthreads();
    s[t] += u;
    __syncthreads();
  }
  int exc = s[t] - v + bsum[b];
#pragma unroll
  for (int k = 0; k < 4; ++k) {
    int i = base + k;
    if (i < tot) { g[i] = exc; exc += d[k]; }
  }
}

// --- K3: scatter packed (src<<9 | dst&511) bucket-major using LDS cursors.
__global__ __launch_bounds__(256) void bscatter_kernel(
    const unsigned int* __restrict__ ew, const unsigned int* __restrict__ flag,
    const int* __restrict__ gscan, unsigned int* __restrict__ pairs, int E, int NB) {
  extern __shared__ int cur[];
  const bool is64 = (*flag == 0u);
  const int t = threadIdx.x, blk = blockIdx.x;
  for (int i = t; i < NB; i += 256) cur[i] = gscan[i * NBLK_C + blk];
  __syncthreads();
  const int chunk = (E + NBLK_C - 1) / NBLK_C;
  const int beg = blk * chunk, end = min(E, beg + chunk);
  for (int e = beg + t; e < end; e += 256) {
    unsigned int s, d;
    if (is64) { s = ew[2 * (size_t)e]; d = ew[2 * (size_t)(E + e)]; }
    else      { s = ew[(size_t)e];     d = ew[(size_t)E + e]; }
    int pos = atomicAdd(&cur[d >> NPB_SHIFT], 1);
    pairs[pos] = (s << NPB_SHIFT) | (d & (NPB - 1));
  }
}

// --- K4: per-bucket LDS counting sort -> rowptr (direct) + dense col writes.
__global__ __launch_bounds__(256) void bsort_kernel(
    const unsigned int* __restrict__ pairs, const int* __restrict__ gscan,
    int* __restrict__ rowptr, int* __restrict__ col, int E, int N, int NB) {
  __shared__ int cnt[NPB];
  __shared__ int scn[NPB];
  __shared__ int cur[NPB];
  __shared__ int part[256];
  const int t = threadIdx.x, b = blockIdx.x;
  const int base = gscan[(size_t)b * NBLK_C];
  const int bend = (b + 1 < NB) ? gscan[(size_t)(b + 1) * NBLK_C] : E;
  const int n0 = b << NPB_SHIFT;

  cnt[2 * t] = 0; cnt[2 * t + 1] = 0;
  __syncthreads();
  for (int j = base + t; j < bend; j += 256)
    atomicAdd(&cnt[pairs[j] & (NPB - 1)], 1);
  __syncthreads();

  int c0 = cnt[2 * t], c1 = cnt[2 * t + 1];
  part[t] = c0 + c1;
  __syncthreads();
  for (int off = 1; off < 256; off <<= 1) {
    int u = (t >= off) ? part[t - off] : 0;
    __syncthreads();
    part[t] += u;
    __syncthreads();
  }
  int exc = part[t] - (c0 + c1);
  scn[2 * t] = exc; scn[2 * t + 1] = exc + c0;
  cur[2 * t] = base + exc; cur[2 * t + 1] = base + exc + c0;

  int g0 = n0 + 2 * t, g1 = n0 + 2 * t + 1;
  if (g0 < N) rowptr[g0] = base + scn[2 * t];
  if (g1 < N) rowptr[g1] = base + scn[2 * t + 1];
  if (b == NB - 1 && t == 0) rowptr[N] = E;
  __syncthreads();

  for (int j = base + t; j < bend; j += 256) {
    unsigned int p = pairs[j];
    int pos = atomicAdd(&cur[p & (NPB - 1)], 1);
    col[pos] = (int)(p >> NPB_SHIFT);
  }
}

// --- cast x (f32) -> xb (bf16), vectorized
__global__ __launch_bounds__(256) void castx_kernel(
    const float4* __restrict__ X, ushort4* __restrict__ XB, int tot4) {
  int i = blockIdx.x * 256 + threadIdx.x;
  if (i >= tot4) return;
  float4 v = X[i];
  ushort4 r;
  r.x = f2b(v.x); r.y = f2b(v.y); r.z = f2b(v.z); r.w = f2b(v.w);
  XB[i] = r;
}

// --- weight transpose + cast: Wt[fo][k] = bf16(W[k][fo]); zero-pad fo>=Fo, k>=Fi
__global__ __launch_bounds__(256) void transw_kernel(
    const float* __restrict__ W, unsigned short* __restrict__ Wt,
    int Fi, int FiPad, int Fo, int FoPad) {
  int i = blockIdx.x * 256 + threadIdx.x;
  if (i >= FoPad * FiPad) return;
  int fo = i / FiPad, k = i - fo * FiPad;
  float v = (fo < Fo && k < Fi) ? W[(size_t)k * Fo + fo] : 0.f;
  Wt[i] = f2b(v);
}

// --- gather over bf16 [N,64] rows (128 B lines): r = X[n] + sum X[col[j]]
// One wave per node, lane = feature. MODE 0: out=bf16(r); MODE 1: out=bf16(relu(r+bias[lane]))
template<int MODE>
__global__ __launch_bounds__(256) void gatherB_kernel(
    const unsigned short* __restrict__ X, const int* __restrict__ rowptr,
    const int* __restrict__ col, unsigned short* __restrict__ out,
    const float* __restrict__ bias, int NBIAS, int N) {
  const int lane = threadIdx.x & 63;
  const int n = blockIdx.x * 4 + (threadIdx.x >> 6);
  if (n >= N) return;
  const int beg = rowptr[n], end = rowptr[n + 1];
  float a0 = b2f(X[(size_t)n * 64 + lane]), a1 = 0.f, a2 = 0.f, a3 = 0.f;
  int j = beg;
  for (; j + 4 <= end; j += 4) {
    int c0 = col[j], c1 = col[j + 1], c2 = col[j + 2], c3 = col[j + 3];
    a0 += b2f(X[(size_t)c0 * 64 + lane]);
    a1 += b2f(X[(size_t)c1 * 64 + lane]);
    a2 += b2f(X[(size_t)c2 * 64 + lane]);
    a3 += b2f(X[(size_t)c3 * 64 + lane]);
  }
  for (; j < end; ++j) a0 += b2f(X[(size_t)col[j] * 64 + lane]);
  float r = a0 + a1 + a2 + a3;
  if (MODE == 1) {
    float bb = (lane < NBIAS) ? bias[lane] : 0.f;
    r = fmaxf(r + bb, 0.f);
  }
  out[(size_t)n * 64 + lane] = f2b(r);
}

// --- bf16 MFMA GEMM: out[n][fo] = act(A[n]@W + b). Block: 4 waves x 16 nodes.
// Wt (B^T, bf16 [FoPad][Fi]) staged in LDS with XOR swizzle; A-frags from global.
template<int Fi, int FoPad, bool RELU>
__global__ __launch_bounds__(256) void gemm_mfma(
    const unsigned short* __restrict__ A, const unsigned short* __restrict__ WtG,
    const float* __restrict__ bias, unsigned short* __restrict__ out,
    int N, int Fo) {
  __shared__ unsigned short Wlds[FoPad * Fi];
  const int t = threadIdx.x;
  const int n0 = blockIdx.x * 64;

  constexpr int NCH = FoPad * Fi / 8;       // 16B chunks
  constexpr int CPR = Fi / 8;               // chunks per row
  for (int c = t; c < NCH; c += 256) {
    int row = c / CPR;
    uint4 v = ((const uint4*)WtG)[c];
    int boff = (c * 16) ^ ((row & 7) << 4);
    *(uint4*)((char*)Wlds + boff) = v;
  }
  __syncthreads();

  const int l = t & 63, w = t >> 6;
  const int kgrp = l >> 4;                  // 0..3
  const int rc = l & 15;
  int arow = n0 + w * 16 + rc;
  int arowc = arow < N ? arow : N - 1;

  constexpr int NF = FoPad / 16;
  f32x4 acc[NF];
#pragma unroll
  for (int nf = 0; nf < NF; ++nf) acc[nf] = (f32x4){0.f, 0.f, 0.f, 0.f};

#pragma unroll
  for (int k0 = 0; k0 < Fi; k0 += 32) {
    bf16x8 a = *(const bf16x8*)(A + (size_t)arowc * Fi + k0 + kgrp * 8);
#pragma unroll
    for (int nf = 0; nf < NF; ++nf) {
      int frow = nf * 16 + rc;
      int boff = ((frow * Fi + k0 + kgrp * 8) * 2) ^ ((frow & 7) << 4);
      bf16x8 b = *(const bf16x8*)((const char*)Wlds + boff);
      acc[nf] = __builtin_amdgcn_mfma_f32_16x16x32_bf16(a, b, acc[nf], 0, 0, 0);
    }
  }

#pragma unroll
  for (int nf = 0; nf < NF; ++nf) {
    int fo = nf * 16 + rc;
    float bs = (fo < Fo) ? bias[fo] : 0.f;
#pragma unroll
    for (int q = 0; q < 4; ++q) {
      int n = n0 + w * 16 + kgrp * 4 + q;
      if (n < N && fo < Fo) {
        float v = acc[nf][q] + bs;
        if (RELU) v = fmaxf(v, 0.f);
        out[(size_t)n * Fo + fo] = f2b(v);
      }
    }
  }
}

// --- fused final: z = v@W2b + b2b (MFMA, K=64, FoPad=48), log_softmax over
// the 40 valid cols, f32 out [N,40]. Row's 48 cols live in 16 lanes x 3 regs;
// max/sum via 4-step shfl_xor within the 16-lane group.
__global__ __launch_bounds__(256) void gemm_sm_kernel(
    const unsigned short* __restrict__ A, const unsigned short* __restrict__ WtG,
    const float* __restrict__ bias, float* __restrict__ out, int N) {
  __shared__ unsigned short Wlds[48 * 64];
  __shared__ float bl[48];
  const int t = threadIdx.x;
  const int n0 = blockIdx.x * 64;

  constexpr int NCH = 48 * 64 / 8;
  constexpr int CPR = 64 / 8;
  for (int c = t; c < NCH; c += 256) {
    int row = c / CPR;
    uint4 v = ((const uint4*)WtG)[c];
    int boff = (c * 16) ^ ((row & 7) << 4);
    *(uint4*)((char*)Wlds + boff) = v;
  }
  if (t < 48) bl[t] = (t < 40) ? bias[t] : 0.f;
  __syncthreads();

  const int l = t & 63, w = t >> 6;
  const int kgrp = l >> 4, rc = l & 15;
  int arow = n0 + w * 16 + rc;
  int arowc = arow < N ? arow : N - 1;

  f32x4 acc[3];
#pragma unroll
  for (int nf = 0; nf < 3; ++nf) acc[nf] = (f32x4){0.f, 0.f, 0.f, 0.f};

#pragma unroll
  for (int k0 = 0; k0 < 64; k0 += 32) {
    bf16x8 a = *(const bf16x8*)(A + (size_t)arowc * 64 + k0 + kgrp * 8);
#pragma unroll
    for (int nf = 0; nf < 3; ++nf) {
      int frow = nf * 16 + rc;
      int boff = ((frow * 64 + k0 + kgrp * 8) * 2) ^ ((frow & 7) << 4);
      bf16x8 b = *(const bf16x8*)((const char*)Wlds + boff);
      acc[nf] = __builtin_amdgcn_mfma_f32_16x16x32_bf16(a, b, acc[nf], 0, 0, 0);
    }
  }

  const bool v2 = (rc < 8);                    // nf=2 -> col=32+rc valid if <40
  float bs0 = bl[rc], bs1 = bl[16 + rc], bs2 = bl[32 + rc];

#pragma unroll
  for (int q = 0; q < 4; ++q) {
    float z0 = acc[0][q] + bs0;
    float z1 = acc[1][q] + bs1;
    float z2 = acc[2][q] + bs2;
    float m = fmaxf(z0, z1);
    if (v2) m = fmaxf(m, z2);
#pragma unroll
    for (int o = 8; o >= 1; o >>= 1) m = fmaxf(m, __shfl_xor(m, o, 64));
    float s = expf(z0 - m) + expf(z1 - m) + (v2 ? expf(z2 - m) : 0.f);
#pragma unroll
    for (int o = 8; o >= 1; o >>= 1) s += __shfl_xor(s, o, 64);
    float ls = m + logf(s);
    int n = n0 + w * 16 + kgrp * 4 + q;
    if (n < N) {
      float* op = out + (size_t)n * 40;
      op[rc] = z0 - ls;
      op[16 + rc] = z1 - ls;
      if (v2) op[32 + rc] = z2 - ls;
    }
  }
}

extern "C" void kernel_launch(void* const* d_in, const int* in_sizes, int n_in,
                              void* d_out, int out_size, void* d_ws, size_t ws_size,
                              hipStream_t stream) {
  const float*        x   = (const float*)d_in[0];
  const unsigned int* ew  = (const unsigned int*)d_in[1];
  const float*        W1a = (const float*)d_in[2];
  const float*        b1a = (const float*)d_in[3];
  const float*        W2a = (const float*)d_in[4];
  const float*        b2a = (const float*)d_in[5];
  const float*        W1b = (const float*)d_in[6];
  const float*        b1b = (const float*)d_in[7];
  const float*        W2b = (const float*)d_in[8];
  const float*        b2b = (const float*)d_in[9];

  const int N = in_sizes[0] / 64;     // 100000
  const int E = in_sizes[1] / 2;      // 1200000
  const int NB = (N + NPB - 1) >> NPB_SHIFT;   // coarse buckets (196)
  float* out = (float*)d_out;

  char* ws = (char*)d_ws;
  size_t off = 0;
  auto alloc = [&](size_t bytes) {
    char* p = ws + off;
    off += (bytes + WS_ALIGN - 1) & ~(size_t)(WS_ALIGN - 1);
    return p;
  };
  unsigned int*  flag   = (unsigned int*)alloc(4);      // offset 0
  float*         zbias  = (float*)alloc(256);           // offset 256, zeroed
  int*           rowptr = (int*)alloc((size_t)(N + 2) * 4);
  int*           gscan  = (int*)alloc((size_t)NB * NBLK_C * 4);
  int*           bsum2  = (int*)alloc(256 * 4);
  int*           col    = (int*)alloc((size_t)E * 4);
  unsigned short* Wt1   = (unsigned short*)alloc((size_t)128 * 64 * 2);
  unsigned short* Wt2   = (unsigned short*)alloc((size_t)128 * 128 * 2);
  unsigned short* Wt3   = (unsigned short*)alloc((size_t)64 * 128 * 2);
  unsigned short* Wt4   = (unsigned short*)alloc((size_t)48 * 64 * 2);
  unsigned short* xb    = (unsigned short*)alloc((size_t)N * 64 * 2);  // bf16 x
  unsigned short* xa    = (unsigned short*)alloc((size_t)N * 64 * 2);  // x+agg1
  unsigned short* mid   = (unsigned short*)alloc((size_t)N * 128 * 2);
  unsigned short* h     = (unsigned short*)alloc((size_t)N * 128 * 2);
  unsigned short* v     = (unsigned short*)alloc((size_t)N * 64 * 2);  // relu(m+Am+b1b)
  // aliases (lifetimes disjoint):
  unsigned int* pairs = (unsigned int*)mid;        // CSR build staging (4.8 MB)
  unsigned short* m   = mid;                       // m = h@W1b padded [N,64] bf16

  hipMemsetAsync(ws, 0, 512, stream);              // flag + zbias
  sniff_kernel<<<1, 256, 0, stream>>>(ew, flag, E);

  // --- CSR build: two-level counting sort (packed pairs)
  const size_t ldsNB = (size_t)NB * 4;
  const int tot = NB * NBLK_C;
  const int nb2 = (tot + SCAN_E - 1) / SCAN_E;
  bhist_kernel<<<NBLK_C, 256, ldsNB, stream>>>(ew, flag, gscan, E, NB);
  pscan1_kernel<<<nb2, SCAN_T, 0, stream>>>(gscan, bsum2, tot);
  pscan2_kernel<<<1, 64, 0, stream>>>(bsum2, nb2);
  pscan3_kernel<<<nb2, SCAN_T, 0, stream>>>(gscan, bsum2, tot);
  bscatter_kernel<<<NBLK_C, 256, ldsNB, stream>>>(ew, flag, gscan, pairs, E, NB);
  bsort_kernel<<<NB, 256, 0, stream>>>(pairs, gscan, rowptr, col, E, N, NB);

  // casts / weight transposes (bf16)
  castx_kernel<<<(N * 16 + 255) / 256, 256, 0, stream>>>((const float4*)x, (ushort4*)xb, N * 16);
  transw_kernel<<<(128 * 64 + 255) / 256, 256, 0, stream>>>(W1a, Wt1, 64, 64, 128, 128);
  transw_kernel<<<(128 * 128 + 255) / 256, 256, 0, stream>>>(W2a, Wt2, 128, 128, 128, 128);
  transw_kernel<<<(64 * 128 + 255) / 256, 256, 0, stream>>>(W1b, Wt3, 128, 128, 40, 64);
  transw_kernel<<<(48 * 64 + 255) / 256, 256, 0, stream>>>(W2b, Wt4, 40, 64, 40, 48);

  const int gGather = (N + 3) / 4;
  const int gGemm = (N + 63) / 64;

  // conv1: xa = x + A x ; mid = relu(xa@W1a+b1a) ; h = relu(mid@W2a+b2a)
  gatherB_kernel<0><<<gGather, 256, 0, stream>>>(xb, rowptr, col, xa, nullptr, 0, N);
  gemm_mfma<64, 128, true><<<gGemm, 256, 0, stream>>>(xa, Wt1, b1a, mid, N, 128);
  gemm_mfma<128, 128, true><<<gGemm, 256, 0, stream>>>(mid, Wt2, b2a, h, N, 128);

  // conv2 (aggregate-after-projection): m = h@W1b (padded 64 cols, no bias)
  gemm_mfma<128, 64, false><<<gGemm, 256, 0, stream>>>(h, Wt3, zbias, m, N, 64);
  // v = bf16(relu(m + A m + b1b))
  gatherB_kernel<1><<<gGather, 256, 0, stream>>>(m, rowptr, col, v, b1b, 40, N);
  // out = log_softmax(v@W2b + b2b)
  gemm_sm_kernel<<<gGemm, 256, 0, stream>>>(v, Wt4, b2b, out, N);
}